// Round 5
// baseline (939.952 us; speedup 1.0000x reference)
//
#include <hip/hip_runtime.h>
#include <cstdint>
#include <cstddef>

typedef _Float16 half8 __attribute__((ext_vector_type(8)));
typedef float f32x16 __attribute__((ext_vector_type(16)));

// ---------------- hf8 decode ----------------
// code: sign(1) | e(4, bias 7) | m(3). e==0 -> m * 2^-9 ; else (1+m/8)*2^(e-7).
__device__ __forceinline__ float dec_hf8(unsigned c) {
    unsigned e = (c >> 3) & 0xFu;
    unsigned m = c & 7u;
    float normal = __uint_as_float(((e + 120u) << 23) | (m << 20));
    float sub = (float)m * 0x1p-9f;
    float mag = (e != 0u) ? normal : sub;
    return (c & 0x80u) ? -mag : mag;
}

// ---------------- prep 1: weight codes (int32) -> fp16 ----------------
__global__ __launch_bounds__(256) void decode_weights(const int* __restrict__ codes,
                                                      _Float16* __restrict__ out,
                                                      long long n8) {
    long long i = (long long)blockIdx.x * 256 + threadIdx.x;
    if (i >= n8) return;
    long long base = i * 8;
    int4 c0 = *(const int4*)(codes + base);
    int4 c1 = *(const int4*)(codes + base + 4);
    half8 h;
    h[0] = (_Float16)dec_hf8((unsigned)c0.x);
    h[1] = (_Float16)dec_hf8((unsigned)c0.y);
    h[2] = (_Float16)dec_hf8((unsigned)c0.z);
    h[3] = (_Float16)dec_hf8((unsigned)c0.w);
    h[4] = (_Float16)dec_hf8((unsigned)c1.x);
    h[5] = (_Float16)dec_hf8((unsigned)c1.y);
    h[6] = (_Float16)dec_hf8((unsigned)c1.z);
    h[7] = (_Float16)dec_hf8((unsigned)c1.w);
    *(half8*)(out + base) = h;
}

// ---------------- prep 2: X fp32 -> fp16 ----------------
__global__ __launch_bounds__(256) void cvt_x(const float* __restrict__ X,
                                             _Float16* __restrict__ out,
                                             long long n8) {
    long long i = (long long)blockIdx.x * 256 + threadIdx.x;
    if (i >= n8) return;
    long long base = i * 8;
    float4 v0 = *(const float4*)(X + base);
    float4 v1 = *(const float4*)(X + base + 4);
    half8 h = {(_Float16)v0.x, (_Float16)v0.y, (_Float16)v0.z, (_Float16)v0.w,
               (_Float16)v1.x, (_Float16)v1.y, (_Float16)v1.z, (_Float16)v1.w};
    *(half8*)(out + base) = h;
}

// ---------------- async global->LDS (16B/lane, wave-uniform LDS base) ----------------
__device__ __forceinline__ void gl_lds16(const void* g, void* l) {
    __builtin_amdgcn_global_load_lds(
        (__attribute__((address_space(1))) void*)(g),
        (__attribute__((address_space(3))) void*)(l), 16, 0, 0);
}

// per-row LDS XOR key: quads {r,r+8,r+16,r+24} hit distinct bank groups;
// per ds_read_b128 this yields exactly 8 words/bank = conflict-free minimum.
#define FKEY(r) (((r) ^ ((r) >> 3)) & 7)

// ---------------- wave-specialized GEMM ----------------
// C = Xh[M][K] * W[N][K]^T + bias. 128x128 tile, BK=64, double-buffered LDS.
// 6 waves: wid 0..3 consumers (2x2 of 64x64, 32x32x16 f16 MFMA; zero vmem in loop),
//          wid 4 stages A, wid 5 stages B via global_load_lds (16 issues/tile).
// One __syncthreads per K-iter: producer issues tile kt+1 at iter start, the
// barrier's auto vmcnt(0) (producer waves only) drains it after the consumers'
// compute phase has overlapped the DMA latency.
__global__ __launch_bounds__(384) void hgemm_ws(const _Float16* __restrict__ Xh,
                                                const _Float16* __restrict__ W,
                                                const int* __restrict__ bias_codes,
                                                float* __restrict__ C,
                                                int M, int N, int K) {
    __shared__ _Float16 SA[2][128 * 64];
    __shared__ _Float16 SB[2][128 * 64];

    const int tid  = threadIdx.x;
    const int lane = tid & 63;
    const int wid  = tid >> 6;

    // block swizzle: panels of 8 m-tiles per n-tile for W-panel L2 reuse
    const int nTiles = gridDim.x, mTiles = gridDim.y;
    int bid = blockIdx.y * nTiles + blockIdx.x;
    const int GM = 8;
    int group = bid / (GM * nTiles);
    int inGrp = bid % (GM * nTiles);
    int mStart = group * GM;
    int gm = (mTiles - mStart < GM) ? (mTiles - mStart) : GM;
    const int mB = (mStart + inGrp % gm) << 7;
    const int nB = (inGrp / gm) << 7;

    const int kIters = K >> 6;

    if (wid >= 4) {
        // ---------------- producer: wid4 -> SA (Xh), wid5 -> SB (W) ----------------
        const _Float16* src = (wid == 4) ? Xh : W;
        const int rowB = (wid == 4) ? mB : nB;
        char* dst0 = (char*)((wid == 4) ? SA[0] : SB[0]);
        char* dst1 = (char*)((wid == 4) ? SA[1] : SB[1]);
        // per-lane global pointers (iter-invariant): chunk p=is*64+lane, row=p>>3,
        // source 16B-chunk g = (p&7) ^ FKEY(row); LDS dest = p*16 (linear).
        const _Float16* gptr[16];
#pragma unroll
        for (int is = 0; is < 16; ++is) {
            int p = is * 64 + lane;
            int row = p >> 3;
            int g = (p & 7) ^ FKEY(row);
            gptr[is] = src + (size_t)(rowB + row) * K + (g << 3);
        }
#pragma unroll
        for (int is = 0; is < 16; ++is)       // tile 0 -> buffer 0
            gl_lds16(gptr[is], dst0 + (is << 10));
        __syncthreads();                      // drain tile 0
        for (int kt = 0; kt < kIters; ++kt) {
            int nt = kt + 1;
            if (nt < kIters) {
                char* d = (nt & 1) ? dst1 : dst0;
                const size_t off = (size_t)nt * 64;
#pragma unroll
                for (int is = 0; is < 16; ++is)
                    gl_lds16(gptr[is] + off, d + (is << 10));
            }
            __syncthreads();  // consumers finished tile kt; tile kt+1 drained
        }
        return;
    }

    // ---------------- consumer ----------------
    const int wm = (wid >> 1) << 6;
    const int wn = (wid & 1) << 6;
    const int fr = lane & 31;    // fragment row/col
    const int kh = lane >> 5;    // k-half selector
    const int fkey = FKEY(fr);   // subtile i uses fkey ^ (i<<2)  (FKEY(32i+fr))

    f32x16 acc[2][2] = {};

    __syncthreads();             // tile 0 ready
    for (int kt = 0; kt < kIters; ++kt) {
        const _Float16* As = SA[kt & 1];
        const _Float16* Bs = SB[kt & 1];
#pragma unroll
        for (int ks = 0; ks < 4; ++ks) {
            const int lc = (ks << 1) + kh;   // logical 16B chunk in row
            half8 a[2], bb[2];
#pragma unroll
            for (int i = 0; i < 2; ++i) {
                const int co = ((lc ^ fkey ^ (i << 2)) << 3);
                a[i]  = *(const half8*)(As + ((wm + (i << 5) + fr) << 6) + co);
                bb[i] = *(const half8*)(Bs + ((wn + (i << 5) + fr) << 6) + co);
            }
#pragma unroll
            for (int mi = 0; mi < 2; ++mi)
#pragma unroll
                for (int ni = 0; ni < 2; ++ni)
                    acc[mi][ni] = __builtin_amdgcn_mfma_f32_32x32x16_f16(
                        a[mi], bb[ni], acc[mi][ni], 0, 0, 0);
        }
        __syncthreads();         // frees buffer kt&1 for tile kt+2
    }

    // Epilogue: col = lane&31, row = (reg&3) + 8*(reg>>2) + 4*(lane>>5)  [m74/m101]
#pragma unroll
    for (int ni = 0; ni < 2; ++ni) {
        int col = nB + wn + (ni << 5) + fr;
        float bv = dec_hf8((unsigned)bias_codes[col]);
#pragma unroll
        for (int mi = 0; mi < 2; ++mi) {
            int rbase = mB + wm + (mi << 5) + (kh << 2);
#pragma unroll
            for (int r = 0; r < 16; ++r) {
                int row = rbase + (r & 3) + ((r >> 2) << 3);
                C[(size_t)row * N + col] = acc[mi][ni][r] + bv;
            }
        }
    }
}

// ---------------- correctness parachute ----------------
__global__ void naive_kernel(const float* __restrict__ X, const int* __restrict__ Wc,
                             const int* __restrict__ Bc, float* __restrict__ C,
                             int M, int N, int K) {
    long long idx = (long long)blockIdx.x * 256 + threadIdx.x;
    if (idx >= (long long)M * N) return;
    int m = (int)(idx / N);
    int n = (int)(idx % N);
    float s = dec_hf8((unsigned)Bc[n]);
    const float* x = X + (size_t)m * K;
    const int* w = Wc + (size_t)n * K;
    for (int k = 0; k < K; ++k) s += x[k] * dec_hf8((unsigned)w[k]);
    C[idx] = s;
}

extern "C" void kernel_launch(void* const* d_in, const int* in_sizes, int n_in,
                              void* d_out, int out_size, void* d_ws, size_t ws_size,
                              hipStream_t stream) {
    const float* X  = (const float*)d_in[0];   // x: fp16 promoted to fp32 by harness
    const int*   Wc = (const int*)d_in[1];     // weight codes as int32
    const int*   Bc = (const int*)d_in[2];     // bias codes as int32
    float* C = (float*)d_out;

    long long wn = (long long)in_sizes[1];     // D_OUT * D_IN
    int N = in_sizes[2];                       // D_OUT
    int K = (int)(wn / N);                     // D_IN
    long long xn = (long long)in_sizes[0];
    int M = (int)(xn / K);                     // B*S

    size_t needW = (size_t)wn * sizeof(_Float16);
    size_t needX = (size_t)xn * sizeof(_Float16);
    bool shapes_ok = (M % 128 == 0) && (N % 128 == 0) && (K % 64 == 0) &&
                     (wn % 8 == 0) && (xn % 8 == 0) && (ws_size >= needW + needX);

    if (shapes_ok) {
        _Float16* Wd = (_Float16*)d_ws;
        _Float16* Xh = (_Float16*)((char*)d_ws + needW);
        decode_weights<<<dim3((unsigned)((wn / 8 + 255) / 256)), dim3(256), 0, stream>>>(Wc, Wd, wn / 8);
        cvt_x<<<dim3((unsigned)((xn / 8 + 255) / 256)), dim3(256), 0, stream>>>(X, Xh, xn / 8);
        dim3 grid((unsigned)(N / 128), (unsigned)(M / 128));
        hgemm_ws<<<grid, dim3(384), 0, stream>>>(Xh, Wd, Bc, C, M, N, K);
    } else {
        long long total = (long long)M * N;
        naive_kernel<<<dim3((unsigned)((total + 255) / 256)), dim3(256), 0, stream>>>(X, Wc, Bc, C, M, N, K);
    }
}

// Round 7
// 736.126 us; speedup vs baseline: 1.2769x; 1.2769x over previous
//
#include <hip/hip_runtime.h>
#include <cstdint>
#include <cstddef>

typedef _Float16 half8 __attribute__((ext_vector_type(8)));
typedef __fp16 fp16x2 __attribute__((ext_vector_type(2)));
typedef float f32x16 __attribute__((ext_vector_type(16)));
typedef float f32x2 __attribute__((ext_vector_type(2)));

// ---------------- hf8 decode (scalar, f32) ----------------
// code: sign(1) | e(4, bias 7) | m(3). e==0 -> m * 2^-9 ; else (1+m/8)*2^(e-7).
// NOTE: bit-identical to OCP e4m3fn for all codes except 0x7F/0xFF
// (|x|=480 vs NaN), which cannot occur for this problem's data (|w| <= ~0.15).
__device__ __forceinline__ float dec_hf8(unsigned c) {
    unsigned e = (c >> 3) & 0xFu;
    unsigned m = c & 7u;
    float normal = __uint_as_float(((e + 120u) << 23) | (m << 20));
    float sub = (float)m * 0x1p-9f;
    float mag = (e != 0u) ? normal : sub;
    return (c & 0x80u) ? -mag : mag;
}

// decode 8 e4m3 codes (two packed words) -> 8 fp16, exact
__device__ __forceinline__ half8 dec8(unsigned w0, unsigned w1) {
#if __has_builtin(__builtin_amdgcn_cvt_pk_f32_fp8) && __has_builtin(__builtin_amdgcn_cvt_pkrtz)
    f32x2 a0 = __builtin_amdgcn_cvt_pk_f32_fp8((int)w0, false);
    f32x2 a1 = __builtin_amdgcn_cvt_pk_f32_fp8((int)w0, true);
    f32x2 a2 = __builtin_amdgcn_cvt_pk_f32_fp8((int)w1, false);
    f32x2 a3 = __builtin_amdgcn_cvt_pk_f32_fp8((int)w1, true);
    fp16x2 h0 = __builtin_amdgcn_cvt_pkrtz(a0.x, a0.y);  // exact: e4m3 subset of f16
    fp16x2 h1 = __builtin_amdgcn_cvt_pkrtz(a1.x, a1.y);
    fp16x2 h2 = __builtin_amdgcn_cvt_pkrtz(a2.x, a2.y);
    fp16x2 h3 = __builtin_amdgcn_cvt_pkrtz(a3.x, a3.y);
    half8 r = {(_Float16)h0.x, (_Float16)h0.y, (_Float16)h1.x, (_Float16)h1.y,
               (_Float16)h2.x, (_Float16)h2.y, (_Float16)h3.x, (_Float16)h3.y};
    return r;
#else
    half8 r;
#pragma unroll
    for (int i = 0; i < 4; ++i) r[i] = (_Float16)dec_hf8((w0 >> (8 * i)) & 0xFFu);
#pragma unroll
    for (int i = 0; i < 4; ++i) r[4 + i] = (_Float16)dec_hf8((w1 >> (8 * i)) & 0xFFu);
    return r;
#endif
}

// ---------------- prep 1: repack weight codes int32 -> uint8 ----------------
__global__ __launch_bounds__(256) void repack_codes(const int* __restrict__ codes,
                                                    unsigned* __restrict__ out,
                                                    long long n16) {
    long long i = (long long)blockIdx.x * 256 + threadIdx.x;
    if (i >= n16) return;
    long long base = i * 16;
    unsigned w[4];
#pragma unroll
    for (int q = 0; q < 4; ++q) {
        int4 c = *(const int4*)(codes + base + q * 4);
        w[q] = ((unsigned)c.x & 255u) | (((unsigned)c.y & 255u) << 8) |
               (((unsigned)c.z & 255u) << 16) | (((unsigned)c.w & 255u) << 24);
    }
    *(uint4*)(out + i * 4) = make_uint4(w[0], w[1], w[2], w[3]);
}

// ---------------- prep 2: X fp32 -> fp16 ----------------
__global__ __launch_bounds__(256) void cvt_x(const float* __restrict__ X,
                                             _Float16* __restrict__ out,
                                             long long n8) {
    long long i = (long long)blockIdx.x * 256 + threadIdx.x;
    if (i >= n8) return;
    long long base = i * 8;
    float4 v0 = *(const float4*)(X + base);
    float4 v1 = *(const float4*)(X + base + 4);
    half8 h = {(_Float16)v0.x, (_Float16)v0.y, (_Float16)v0.z, (_Float16)v0.w,
               (_Float16)v1.x, (_Float16)v1.y, (_Float16)v1.z, (_Float16)v1.w};
    *(half8*)(out + base) = h;
}

// ---------------- async global->LDS (16B/lane, wave-uniform LDS base) ----------------
__device__ __forceinline__ void gl_lds16(const void* g, void* l) {
    __builtin_amdgcn_global_load_lds(
        (__attribute__((address_space(1))) void*)(g),
        (__attribute__((address_space(3))) void*)(l), 16, 0, 0);
}

// per-row LDS XOR key: quads {r,r+8,r+16,r+24} hit distinct bank groups;
// ds_read_b128 fragment reads land exactly 8 words/bank = conflict-free minimum.
// (verified correct + 0 conflicts in round 5)
#define FKEY(r) (((r) ^ ((r) >> 3)) & 7)

// ---------------- GEMM: C = Xh[M][K] * W8[N][K]^T + bias ----------------
// 128x256 tile, BK=64, single-buffered LDS (A 16KB fp16 + B 32KB fp16 = 48KB).
// 512 threads = 8 waves as 2(m) x 4(n); each wave 64x64 via 2x2 of 32x32x16 f16 MFMA.
// A staged via global_load_lds (FKEY-swizzled source chunks); B staged via
// uint4 code loads + HW e4m3->f16 decode + swizzled ds_write_b128.
// XCD mapping (M/128==32): bid&7 = m-group of 4 tiles pinned to one XCD;
// sweep n-tiles j with i fastest -> X panels (4MB) live in that XCD's L2,
// W panel (1MB fp8) shared by 4 co-resident blocks; X+W (79MB) L3-resident.
__global__ __launch_bounds__(512) void hgemm_x2(const _Float16* __restrict__ Xh,
                                                const unsigned char* __restrict__ W8,
                                                const int* __restrict__ bias_codes,
                                                float* __restrict__ C,
                                                int M, int N, int K) {
    __shared__ _Float16 As[128 * 64];
    __shared__ _Float16 Bs[256 * 64];

    const int tid  = threadIdx.x;
    const int lane = tid & 63;
    const int wid  = tid >> 6;

    const int nT = N >> 8;           // 256-wide n-tiles
    const int mT = M >> 7;           // 128-tall m-tiles
    int mTile, nTile;
    int bid = blockIdx.x;
    if (mT == 32) {                  // XCD-aware mapping (bench shape)
        int x = bid & 7;             // m-group == XCD (heuristic: bid%8 round-robin)
        int l = bid >> 3;
        mTile = (x << 2) + (l & 3);  // i fastest: 4 sharers of a W panel co-resident
        nTile = l >> 2;
    } else {
        mTile = bid / nT;
        nTile = bid % nT;
    }
    const int mB = mTile << 7;
    const int nB = nTile << 8;

    const int kIters = K >> 6;

    // A staging: 128x64 fp16 = 1024 x 16B chunks; 2 issues x 512 threads.
    const _Float16* aptr[2];
#pragma unroll
    for (int it = 0; it < 2; ++it) {
        int p = it * 512 + tid;
        int row = p >> 3;
        int g = (p & 7) ^ FKEY(row);
        aptr[it] = Xh + (size_t)(mB + row) * K + (g << 3);
    }
    char* as_base = (char*)As;

    // B staging: 256 rows x 64 codes; thread t: row=t>>1, half-row hc=t&1 (32 codes).
    const int brow = tid >> 1;
    const int bhc  = tid & 1;
    const unsigned char* bptr = W8 + (size_t)(nB + brow) * K + (bhc << 5);
    const int bfk = FKEY(brow);
    // decoded chunks g = bhc*4 + {0,1,2,3}; LDS half-offset = (g ^ bfk) * 8
    _Float16* brow_lds = Bs + (brow << 6);
    const int bg0 = bhc << 2;

    const int wm = (wid >> 2) << 6;  // 2 m-slots
    const int wn = (wid & 3) << 6;   // 4 n-slots
    const int fr = lane & 31;        // fragment row/col
    const int kh = lane >> 5;        // k-half selector
    const int fkey = FKEY(fr);       // subtile i uses fkey ^ (i<<2)

    f32x16 acc[2][2] = {};

    for (int kt = 0; kt < kIters; ++kt) {
        // A -> LDS via DMA
#pragma unroll
        for (int it = 0; it < 2; ++it) {
            gl_lds16(aptr[it], as_base + ((it * 512 + tid) << 4));
            aptr[it] += 64;
        }
        // B codes -> decode -> LDS
        uint4 q0 = *(const uint4*)(bptr);
        uint4 q1 = *(const uint4*)(bptr + 16);
        bptr += 64;
        half8 d0 = dec8(q0.x, q0.y);
        half8 d1 = dec8(q0.z, q0.w);
        half8 d2 = dec8(q1.x, q1.y);
        half8 d3 = dec8(q1.z, q1.w);
        *(half8*)(brow_lds + (((bg0 + 0) ^ bfk) << 3)) = d0;
        *(half8*)(brow_lds + (((bg0 + 1) ^ bfk) << 3)) = d1;
        *(half8*)(brow_lds + (((bg0 + 2) ^ bfk) << 3)) = d2;
        *(half8*)(brow_lds + (((bg0 + 3) ^ bfk) << 3)) = d3;
        __syncthreads();  // drains A DMA (vmcnt) + B LDS writes (lgkm)

#pragma unroll
        for (int ks = 0; ks < 4; ++ks) {
            const int lc = (ks << 1) + kh;   // logical 16B chunk in row
            half8 a[2], bb[2];
#pragma unroll
            for (int i = 0; i < 2; ++i) {
                const int co = ((lc ^ fkey ^ (i << 2)) << 3);
                a[i]  = *(const half8*)(As + ((wm + (i << 5) + fr) << 6) + co);
                bb[i] = *(const half8*)(Bs + ((wn + (i << 5) + fr) << 6) + co);
            }
#pragma unroll
            for (int mi = 0; mi < 2; ++mi)
#pragma unroll
                for (int ni = 0; ni < 2; ++ni)
                    acc[mi][ni] = __builtin_amdgcn_mfma_f32_32x32x16_f16(
                        a[mi], bb[ni], acc[mi][ni], 0, 0, 0);
        }
        __syncthreads();
    }

    // Epilogue: col = lane&31, row = (reg&3) + 8*(reg>>2) + 4*(lane>>5)  [m74/m101]
#pragma unroll
    for (int ni = 0; ni < 2; ++ni) {
        int col = nB + wn + (ni << 5) + fr;
        float bv = dec_hf8((unsigned)bias_codes[col]);
#pragma unroll
        for (int mi = 0; mi < 2; ++mi) {
            int rbase = mB + wm + (mi << 5) + (kh << 2);
#pragma unroll
            for (int r = 0; r < 16; ++r) {
                int row = rbase + (r & 3) + ((r >> 2) << 3);
                C[(size_t)row * N + col] = acc[mi][ni][r] + bv;
            }
        }
    }
}

// ---------------- correctness parachute ----------------
__global__ void naive_kernel(const float* __restrict__ X, const int* __restrict__ Wc,
                             const int* __restrict__ Bc, float* __restrict__ C,
                             int M, int N, int K) {
    long long idx = (long long)blockIdx.x * 256 + threadIdx.x;
    if (idx >= (long long)M * N) return;
    int m = (int)(idx / N);
    int n = (int)(idx % N);
    float s = dec_hf8((unsigned)Bc[n]);
    const float* x = X + (size_t)m * K;
    const int* w = Wc + (size_t)n * K;
    for (int k = 0; k < K; ++k) s += x[k] * dec_hf8((unsigned)w[k]);
    C[idx] = s;
}

extern "C" void kernel_launch(void* const* d_in, const int* in_sizes, int n_in,
                              void* d_out, int out_size, void* d_ws, size_t ws_size,
                              hipStream_t stream) {
    const float* X  = (const float*)d_in[0];   // x: fp16 promoted to fp32 by harness
    const int*   Wc = (const int*)d_in[1];     // weight codes as int32
    const int*   Bc = (const int*)d_in[2];     // bias codes as int32
    float* C = (float*)d_out;

    long long wn = (long long)in_sizes[1];     // D_OUT * D_IN
    int N = in_sizes[2];                       // D_OUT
    int K = (int)(wn / N);                     // D_IN
    long long xn = (long long)in_sizes[0];
    int M = (int)(xn / K);                     // B*S

    size_t needW = (size_t)wn;                 // uint8 codes
    size_t needX = (size_t)xn * sizeof(_Float16);
    bool shapes_ok = (M % 128 == 0) && (N % 256 == 0) && (K % 64 == 0) &&
                     (wn % 16 == 0) && (xn % 8 == 0) && (ws_size >= needW + needX + 16);

    if (shapes_ok) {
        unsigned char* W8 = (unsigned char*)d_ws;
        _Float16* Xh = (_Float16*)((char*)d_ws + ((needW + 15) & ~(size_t)15));
        repack_codes<<<dim3((unsigned)((wn / 16 + 255) / 256)), dim3(256), 0, stream>>>(
            Wc, (unsigned*)W8, wn / 16);
        cvt_x<<<dim3((unsigned)((xn / 8 + 255) / 256)), dim3(256), 0, stream>>>(X, Xh, xn / 8);
        unsigned blocks = (unsigned)((M / 128) * (N / 256));
        hgemm_x2<<<dim3(blocks), dim3(512), 0, stream>>>(Xh, W8, Bc, C, M, N, K);
    } else {
        long long total = (long long)M * N;
        naive_kernel<<<dim3((unsigned)((total + 255) / 256)), dim3(256), 0, stream>>>(X, Wc, Bc, C, M, N, K);
    }
}